// Round 14
// baseline (247.613 us; speedup 1.0000x reference)
//
#include <hip/hip_runtime.h>
#include <hip/hip_bf16.h>

#define BB 2
#define NN 8192
#define SPL 16
#define CAND (NN/SPL)
#define NPTS (BB*NN)

// ---- workspace layout (units: 4-byte words), total ~26.5 MB ----
#define POS4_OFF 0u                     /* 65,536 w float4 (x,y,z,|c|^2) */
#define PART_OFF 65536u                 /* [256][NPTS] = 4,194,304 w */
#define IDX_OFF  4259840u               /* 262,144 w */
#define WT_OFF   4521984u               /* 4 mats x 4096 bf16 = 8,192 w */
#define QB_OFF   4530176u               /* 1,048,576 w */
#define KVB_OFF  5578752u               /* 1,048,576 w packed bf16 k|v */

typedef __attribute__((ext_vector_type(8))) short bf16x8;
typedef __attribute__((ext_vector_type(4))) float f32x4;

__device__ __forceinline__ unsigned umn(unsigned a, unsigned b) {
#if __has_builtin(__builtin_elementwise_min)
  return __builtin_elementwise_min(a, b);
#else
  return a < b ? a : b;
#endif
}
__device__ __forceinline__ unsigned umx(unsigned a, unsigned b) {
#if __has_builtin(__builtin_elementwise_max)
  return __builtin_elementwise_max(a, b);
#else
  return a < b ? b : a;
#endif
}

__device__ inline unsigned short f2bf(float x) {
  __hip_bfloat16 b = __float2bfloat16(x);
  return *(unsigned short*)&b;
}

// column-block rotate swizzle for conflict-free ds_read_b128 fragments
#define HCOL(c, j) ((((((c) >> 3) + (j)) & 7) << 3) | ((c) & 7))

// ============================ S1: pos4 + wt bf16-T staging (tiny) =============
__global__ __launch_bounds__(256) void s1_stage(
    const float* __restrict__ pos,
    const float* __restrict__ pe_w2, const float* __restrict__ at_w1,
    const float* __restrict__ at_w2, const float* __restrict__ out_w,
    float* __restrict__ ws)
{
  const int t = blockIdx.x * 256 + threadIdx.x;
  if (t < NPTS) {
    float x = pos[t * 3 + 0], y = pos[t * 3 + 1], z = pos[t * 3 + 2];
    float* o = ws + POS4_OFF + t * 4;
    o[0] = x; o[1] = y; o[2] = z;
    o[3] = fmaf(x, x, fmaf(y, y, z * z));
    return;
  }
  const int u = t - NPTS;   // 16384 entries: wt[m*4096+f*64+c] = W_m[c*64+f]
  const float* s;
  switch (u >> 12) {
    case 0: s = pe_w2; break;
    case 1: s = at_w1; break;
    case 2: s = at_w2; break;
    default: s = out_w; break;
  }
  const int idx = u & 4095, f = idx >> 6, c = idx & 63;
  ((unsigned short*)(ws + WT_OFF))[u] = f2bf(s[c * 64 + f]);
}

// ============================ S2: fused KNN + emb/qkv (role-split) ============
// blocks [0,1024)   : KNN batch-16 OEMS, pos4 distance
// blocks [1024,1536): x=emb(feat); q,k,v via 4-pass 24KB LDS staging
__global__ __launch_bounds__(256) void s2_knn_qkv(
    const float* __restrict__ feat,
    const float* __restrict__ emb_w, const float* __restrict__ emb_b,
    const float* __restrict__ wq, const float* __restrict__ wk,
    const float* __restrict__ wv,
    float* __restrict__ ws)
{
  __shared__ __align__(16) float smem[6144];   // 24 KB: wl[4096] | xl[2048]
  const int tid = threadIdx.x;
  const int bx = blockIdx.x;
  const float* pos4 = ws + POS4_OFF;
  unsigned* part = (unsigned*)ws + PART_OFF;
  float* qg = ws + QB_OFF;
  unsigned* kvp = (unsigned*)ws + KVB_OFF;

  if (bx < 1024) {
    // ---------------- role A: KNN ----------------
    constexpr int OE[63][2] = {
      {0,1},{2,3},{4,5},{6,7},{8,9},{10,11},{12,13},{14,15},
      {0,2},{1,3},{4,6},{5,7},{8,10},{9,11},{12,14},{13,15},
      {1,2},{5,6},{9,10},{13,14},
      {0,4},{1,5},{2,6},{3,7},{8,12},{9,13},{10,14},{11,15},
      {2,4},{3,5},{10,12},{11,13},
      {1,2},{3,4},{5,6},{9,10},{11,12},{13,14},
      {0,8},{1,9},{2,10},{3,11},{4,12},{5,13},{6,14},{7,15},
      {4,8},{5,9},{6,10},{7,11},
      {2,4},{3,5},{6,8},{7,9},{10,12},{11,13},
      {1,2},{3,4},{5,6},{7,8},{9,10},{11,12},{13,14}
    };
    const int g = (bx & 63) * 256 + tid;
    const int s = bx >> 6;
    const int bu = __builtin_amdgcn_readfirstlane(g >> 13);
    const float4* allp = (const float4*)pos4;
    const float4 q = allp[g];
    const float qx2 = -2.f * q.x, qy2 = -2.f * q.y, qz2 = -2.f * q.z;
    const float sqq = q.w + 1e-5f;   // keeps d2>0 under rounding: no fmax
    const float4* cand = allp + (bu * NN + s * CAND);
    const unsigned jb = (unsigned)(s * CAND);
    unsigned m[16];
#pragma unroll
    for (int i = 0; i < 16; i++) m[i] = 0xFFFFFFFFu;
    for (int j0 = 0; j0 < CAND; j0 += 16) {
      unsigned b[16];
#pragma unroll
      for (int i = 0; i < 16; i++) {
        float4 cp = cand[j0 + i];              // wave-uniform -> scalar loads
        float d2 = fmaf(cp.x, qx2, fmaf(cp.y, qy2, fmaf(cp.z, qz2, cp.w + sqq)));
        b[i] = (__float_as_uint(d2) & 0xFFFFE000u) | (jb + (unsigned)(j0 + i));
      }
#pragma unroll
      for (int cc = 0; cc < 63; cc++) {        // OEMS-16 sort DESC
        const int x = OE[cc][0], y = OE[cc][1];
        unsigned lo = umn(b[x], b[y]);
        unsigned hi = umx(b[x], b[y]);
        b[x] = hi; b[y] = lo;
      }
#pragma unroll
      for (int i = 0; i < 16; i++) m[i] = umn(m[i], b[i]);
#pragma unroll
      for (int d = 8; d; d >>= 1) {            // bitonic clean -> asc
#pragma unroll
        for (int i = 0; i < 16; i++) {
          if ((i & d) == 0) {
            const int l = i | d;
            unsigned lo = umn(m[i], m[l]);
            unsigned hi = umx(m[i], m[l]);
            m[i] = lo; m[l] = hi;
          }
        }
      }
    }
#pragma unroll
    for (int i = 0; i < 16; i++)
      part[(unsigned)(s * 16 + i) * NPTS + (unsigned)g] = m[i];
  } else {
    // ---------------- role B: emb + qkv, 4-pass staging ----------------
    float* wl = smem;            // 4096 floats (16 KB)
    float* xl = smem + 4096;     // 2048 floats (8 KB)
    const int vb = bx - 1024;
    const int col = tid & 63;
    const int rg = tid >> 6;
    const int row0 = vb * 32 + rg * 8;
    const int rowu = __builtin_amdgcn_readfirstlane(row0);
    for (int i = tid; i < 4096; i += 256) wl[i] = emb_w[i];
    __syncthreads();
    {
      float acc[8];
      float bias = emb_b[col];
#pragma unroll
      for (int r = 0; r < 8; r++) acc[r] = bias;
      for (int c = 0; c < 64; c++) {
        float w = wl[c * 64 + col];
        const float* fp = feat + rowu * 64 + c;   // uniform -> scalar loads
#pragma unroll
        for (int r = 0; r < 8; r++) acc[r] = fmaf(fp[r * 64], w, acc[r]);
      }
#pragma unroll
      for (int r = 0; r < 8; r++) xl[(rg * 8 + r) * 64 + col] = acc[r];
    }
    __syncthreads();
    for (int i = tid; i < 4096; i += 256) wl[i] = wq[i];
    __syncthreads();
    {
      float aq[8];
#pragma unroll
      for (int r = 0; r < 8; r++) aq[r] = 0.f;
      for (int c = 0; c < 64; c++) {
        float w = wl[c * 64 + col];
#pragma unroll
        for (int r = 0; r < 8; r++)
          aq[r] = fmaf(xl[(rg * 8 + r) * 64 + c], w, aq[r]);
      }
#pragma unroll
      for (int r = 0; r < 8; r++) qg[(row0 + r) * 64 + col] = aq[r];
    }
    __syncthreads();
    for (int i = tid; i < 4096; i += 256) wl[i] = wk[i];
    __syncthreads();
    float ak[8];
    {
#pragma unroll
      for (int r = 0; r < 8; r++) ak[r] = 0.f;
      for (int c = 0; c < 64; c++) {
        float w = wl[c * 64 + col];
#pragma unroll
        for (int r = 0; r < 8; r++)
          ak[r] = fmaf(xl[(rg * 8 + r) * 64 + c], w, ak[r]);
      }
    }
    __syncthreads();
    for (int i = tid; i < 4096; i += 256) wl[i] = wv[i];
    __syncthreads();
    {
      float av[8];
#pragma unroll
      for (int r = 0; r < 8; r++) av[r] = 0.f;
      for (int c = 0; c < 64; c++) {
        float w = wl[c * 64 + col];
#pragma unroll
        for (int r = 0; r < 8; r++)
          av[r] = fmaf(xl[(rg * 8 + r) * 64 + c], w, av[r]);
      }
#pragma unroll
      for (int r = 0; r < 8; r++)
        kvp[(row0 + r) * 64 + col] =
            ((unsigned)f2bf(av[r]) << 16) | (unsigned)f2bf(ak[r]);
    }
  }
}

// ============================ S3: merge 16 sorted 16-lists (coalesced) ========
__global__ __launch_bounds__(256) void s3_merge(const float* __restrict__ ws_ro,
                                                int* __restrict__ knn_idx)
{
  const unsigned* part = (const unsigned*)ws_ro + PART_OFF;
  const int g = blockIdx.x * 256 + threadIdx.x;
  unsigned run[16];
#pragma unroll
  for (int i = 0; i < 16; i++) run[i] = part[i * NPTS + g];
#pragma unroll
  for (int l = 1; l < SPL; l++) {
#pragma unroll
    for (int i = 0; i < 16; i++)
      run[i] = umn(run[i], part[(l * 16 + 15 - i) * NPTS + g]);
#pragma unroll
    for (int d = 8; d; d >>= 1) {
#pragma unroll
      for (int i = 0; i < 16; i++) {
        if ((i & d) == 0) {
          const int l2 = i | d;
          unsigned lo = umn(run[i], run[l2]);
          unsigned hi = umx(run[i], run[l2]);
          run[i] = lo; run[l2] = hi;
        }
      }
    }
  }
  const int base = (g >> 13) * NN;
  int outv[16];
#pragma unroll
  for (int i = 0; i < 16; i++) outv[i] = base + (int)(run[i] & 0x1FFFu);
  int4* o = (int4*)(knn_idx + g * 16);
  o[0] = make_int4(outv[0], outv[1], outv[2], outv[3]);
  o[1] = make_int4(outv[4], outv[5], outv[6], outv[7]);
  o[2] = make_int4(outv[8], outv[9], outv[10], outv[11]);
  o[3] = make_int4(outv[12], outv[13], outv[14], outv[15]);
}

// ============================ S4: MFMA attn, PAIRED phases ====================
// Two points per iteration share each latency epoch: both points' gathers
// issued up front, then 2x mv per phase back-to-back. Halves stall epochs.
// LDS 18 KB; Bf in regs; lb(256,2) (R9-proven no-spill budget).
__device__ inline void mv(const unsigned short* hm, const bf16x8 B[4][2],
                          const float bias[4], int ln, int s0, int s1,
                          f32x4 acc[4])
{
  bf16x8 a0 = *(const bf16x8*)(hm + ln * 64 + s0);
  bf16x8 a1 = *(const bf16x8*)(hm + ln * 64 + s1);
#pragma unroll
  for (int t = 0; t < 4; t++) {
    f32x4 a = {bias[t], bias[t], bias[t], bias[t]};
    a = __builtin_amdgcn_mfma_f32_16x16x32_bf16(a0, B[t][0], a, 0, 0, 0);
    a = __builtin_amdgcn_mfma_f32_16x16x32_bf16(a1, B[t][1], a, 0, 0, 0);
    acc[t] = a;
  }
}

__global__ __launch_bounds__(256, 2) void s4_attn(
    const float* __restrict__ ws_ro, const float* __restrict__ feat,
    const float* __restrict__ pe_w1, const float* __restrict__ pe_b1,
    const float* __restrict__ pe_b2, const float* __restrict__ at_b1,
    const float* __restrict__ at_b2, const float* __restrict__ out_b,
    const int* __restrict__ knn, float* __restrict__ out)
{
  __shared__ unsigned short hma[4][2][1024];  // 2 bufs per wave (16 KB)
  __shared__ unsigned short resm[1024];       // 16 points x 64 bf16 (2 KB)
  const float* pos4 = ws_ro + POS4_OFF;
  const float* qg = ws_ro + QB_OFF;
  const unsigned* kvp = (const unsigned*)ws_ro + KVB_OFF;
  const unsigned short* wt = (const unsigned short*)(ws_ro + WT_OFF);

  const int tid = threadIdx.x;
  const int wid = tid >> 6, lane = tid & 63;
  const int ln = lane & 15, quad = lane >> 4;
  unsigned short* hmA = hma[wid][0];
  unsigned short* hmB = hma[wid][1];
  const int s0 = ((quad + ln) & 7) << 3;
  const int s1 = ((4 + quad + ln) & 7) << 3;

  bf16x8 Bf[3][4][2];
#pragma unroll
  for (int m = 0; m < 3; m++)
#pragma unroll
    for (int t = 0; t < 4; t++)
#pragma unroll
      for (int ks = 0; ks < 2; ks++)
        Bf[m][t][ks] = *(const bf16x8*)(wt + m * 4096 + (t * 16 + ln) * 64 +
                                        ks * 32 + quad * 8);
  bf16x8 bo[2];
#pragma unroll
  for (int ks = 0; ks < 2; ks++)
    bo[ks] = *(const bf16x8*)(wt + 3 * 4096 + (wid * 16 + ln) * 64 +
                              ks * 32 + quad * 8);

  float pw10 = pe_w1[lane], pw11 = pe_w1[64 + lane], pw12 = pe_w1[128 + lane];
  float pb1 = pe_b1[lane];
  float bpe[4], ba1[4], ba2[4];
#pragma unroll
  for (int t = 0; t < 4; t++) {
    bpe[t] = pe_b2[t * 16 + ln];
    ba1[t] = at_b1[t * 16 + ln];
    ba2[t] = at_b2[t * 16 + ln];
  }
  const float4* pp4 = (const float4*)pos4;
  const int p0 = blockIdx.x * 16 + wid * 4;

  for (int pr = 0; pr < 2; pr++) {
    const int pa = p0 + pr * 2, pb_ = pa + 1;
    const int psa = __builtin_amdgcn_readfirstlane(pa);
    const int psb = __builtin_amdgcn_readfirstlane(pb_);
    // ---- indices for both points ----
    int jja[16], jjb[16];
    {
      const int4* i4a = (const int4*)(knn + psa * 16);
      const int4* i4b = (const int4*)(knn + psb * 16);
#pragma unroll
      for (int u = 0; u < 4; u++) {
        int4 ta = i4a[u], tb = i4b[u];
        jja[u*4+0] = ta.x; jja[u*4+1] = ta.y; jja[u*4+2] = ta.z; jja[u*4+3] = ta.w;
        jjb[u*4+0] = tb.x; jjb[u*4+1] = tb.y; jjb[u*4+2] = tb.z; jjb[u*4+3] = tb.w;
      }
    }
    // ---- both points' kv + q gathers issued up front ----
    unsigned kva[4][4], kvb[4][4];
#pragma unroll
    for (int r = 0; r < 4; r++) {
      const unsigned* ka = kvp + jja[quad * 4 + r] * 64 + ln;
      const unsigned* kb = kvp + jjb[quad * 4 + r] * 64 + ln;
#pragma unroll
      for (int t = 0; t < 4; t++) { kva[r][t] = ka[t * 16]; kvb[r][t] = kb[t * 16]; }
    }
    float qva[4], qvb[4];
#pragma unroll
    for (int t = 0; t < 4; t++) {
      qva[t] = qg[pa * 64 + t * 16 + ln];
      qvb[t] = qg[pb_ * 64 + t * 16 + ln];
    }
    // ---- h1 for both points ----
    const float4 mpa = pp4[psa];
    const float4 mpb = pp4[psb];
#pragma unroll
    for (int j = 0; j < 16; j++) {
      const float4 na = pp4[jja[j]];
      float h1 = fmaf(na.z - mpa.z, pw12,
                 fmaf(na.y - mpa.y, pw11,
                 fmaf(na.x - mpa.x, pw10, pb1)));
      hmA[j * 64 + HCOL(lane, j)] = f2bf(fmaxf(h1, 0.f));
    }
#pragma unroll
    for (int j = 0; j < 16; j++) {
      const float4 nb = pp4[jjb[j]];
      float h1 = fmaf(nb.z - mpb.z, pw12,
                 fmaf(nb.y - mpb.y, pw11,
                 fmaf(nb.x - mpb.x, pw10, pb1)));
      hmB[j * 64 + HCOL(lane, j)] = f2bf(fmaxf(h1, 0.f));
    }
    // ---- mv1 x2 (16 MFMA back-to-back) ----
    f32x4 accpa[4], accpb[4];
    mv(hmA, Bf[0], bpe, ln, s0, s1, accpa);
    mv(hmB, Bf[0], bpe, ln, s0, s1, accpb);
    // ---- h2 + vpe for both ----
    float vpa[4][4], vpb[4][4];
#pragma unroll
    for (int r = 0; r < 4; r++) {
      const int j = quad * 4 + r;
#pragma unroll
      for (int t = 0; t < 4; t++) {
        unsigned w = kva[r][t];
        float kf = __uint_as_float(w << 16);
        float vf = __uint_as_float(w & 0xFFFF0000u);
        float pe = accpa[t][r];
        vpa[t][r] = vf + pe;
        hmA[j * 64 + HCOL(t * 16 + ln, j)] = f2bf(qva[t] - kf + pe);
      }
#pragma unroll
      for (int t = 0; t < 4; t++) {
        unsigned w = kvb[r][t];
        float kf = __uint_as_float(w << 16);
        float vf = __uint_as_float(w & 0xFFFF0000u);
        float pe = accpb[t][r];
        vpb[t][r] = vf + pe;
        hmB[j * 64 + HCOL(t * 16 + ln, j)] = f2bf(qvb[t] - kf + pe);
      }
    }
    // ---- mv2 x2 ----
    f32x4 accha[4], acchb[4];
    mv(hmA, Bf[1], ba1, ln, s0, s1, accha);
    mv(hmB, Bf[1], ba1, ln, s0, s1, acchb);
    // ---- relu x2 ----
#pragma unroll
    for (int t = 0; t < 4; t++)
#pragma unroll
      for (int r = 0; r < 4; r++) {
        const int j = quad * 4 + r;
        hmA[j * 64 + HCOL(t * 16 + ln, j)] = f2bf(fmaxf(accha[t][r], 0.f));
        hmB[j * 64 + HCOL(t * 16 + ln, j)] = f2bf(fmaxf(acchb[t][r], 0.f));
      }
    // ---- mv3 x2 ----
    f32x4 lga[4], lgb[4];
    mv(hmA, Bf[2], ba2, ln, s0, s1, lga);
    mv(hmB, Bf[2], ba2, ln, s0, s1, lgb);
    // ---- softmax x2 (tiny logits: no max-sub) ----
    const int pba = wid * 4 + pr * 2, pbb = pba + 1;
#pragma unroll
    for (int t = 0; t < 4; t++) {
      float e0 = __expf(lga[t][0] * 0.125f);
      float e1 = __expf(lga[t][1] * 0.125f);
      float e2 = __expf(lga[t][2] * 0.125f);
      float e3 = __expf(lga[t][3] * 0.125f);
      float ss = (e0 + e1) + (e2 + e3);
      float dt = fmaf(e3, vpa[t][3], fmaf(e2, vpa[t][2],
                 fmaf(e1, vpa[t][1], e0 * vpa[t][0])));
      ss += __shfl_xor(ss, 16); ss += __shfl_xor(ss, 32);
      dt += __shfl_xor(dt, 16); dt += __shfl_xor(dt, 32);
      float res = dt / ss;
      if (quad == 0) resm[pba * 64 + HCOL(t * 16 + ln, pba)] = f2bf(res);
    }
#pragma unroll
    for (int t = 0; t < 4; t++) {
      float e0 = __expf(lgb[t][0] * 0.125f);
      float e1 = __expf(lgb[t][1] * 0.125f);
      float e2 = __expf(lgb[t][2] * 0.125f);
      float e3 = __expf(lgb[t][3] * 0.125f);
      float ss = (e0 + e1) + (e2 + e3);
      float dt = fmaf(e3, vpb[t][3], fmaf(e2, vpb[t][2],
                 fmaf(e1, vpb[t][1], e0 * vpb[t][0])));
      ss += __shfl_xor(ss, 16); ss += __shfl_xor(ss, 32);
      dt += __shfl_xor(dt, 16); dt += __shfl_xor(dt, 32);
      float res = dt / ss;
      if (quad == 0) resm[pbb * 64 + HCOL(t * 16 + ln, pbb)] = f2bf(res);
    }
  }
  __syncthreads();
  // epilogue: 16 points = 1 M-tile x 4 N-tiles; wave wid handles N-tile wid
  {
    const int nt = wid;
    float ob = out_b[nt * 16 + ln];
    f32x4 acc = {ob, ob, ob, ob};
#pragma unroll
    for (int ks = 0; ks < 2; ks++) {
      bf16x8 a = *(const bf16x8*)(resm + ln * 64 +
                                  (((ks * 4 + quad + ln) & 7) << 3));
      acc = __builtin_amdgcn_mfma_f32_16x16x32_bf16(a, bo[ks], acc, 0, 0, 0);
    }
#pragma unroll
    for (int r = 0; r < 4; r++) {
      const int pt = blockIdx.x * 16 + quad * 4 + r;
      const int f = nt * 16 + ln;
      out[pt * 64 + f] = acc[r] + feat[pt * 64 + f];
    }
  }
}

// ============================ launcher ========================================
extern "C" void kernel_launch(void* const* d_in, const int* in_sizes, int n_in,
                              void* d_out, int out_size, void* d_ws, size_t ws_size,
                              hipStream_t stream)
{
  (void)in_sizes; (void)n_in; (void)out_size; (void)ws_size;
  const float* pos   = (const float*)d_in[0];
  const float* feat  = (const float*)d_in[1];
  const float* emb_w = (const float*)d_in[2];
  const float* emb_b = (const float*)d_in[3];
  const float* wq    = (const float*)d_in[4];
  const float* wk    = (const float*)d_in[5];
  const float* wv    = (const float*)d_in[6];
  const float* pe_w1 = (const float*)d_in[7];
  const float* pe_b1 = (const float*)d_in[8];
  const float* pe_w2 = (const float*)d_in[9];
  const float* pe_b2 = (const float*)d_in[10];
  const float* at_w1 = (const float*)d_in[11];
  const float* at_b1 = (const float*)d_in[12];
  const float* at_w2 = (const float*)d_in[13];
  const float* at_b2 = (const float*)d_in[14];
  const float* out_w = (const float*)d_in[15];
  const float* out_b = (const float*)d_in[16];
  float* ws = (float*)d_ws;

  s1_stage<<<128, 256, 0, stream>>>(pos, pe_w2, at_w1, at_w2, out_w, ws);
  s2_knn_qkv<<<1536, 256, 0, stream>>>(feat, emb_w, emb_b, wq, wk, wv, ws);
  s3_merge<<<64, 256, 0, stream>>>(ws, (int*)ws + IDX_OFF);
  s4_attn<<<NPTS / 16, 256, 0, stream>>>(ws, feat, pe_w1, pe_b1, pe_b2,
      at_b1, at_b2, out_b, (int*)ws + IDX_OFF, (float*)d_out);
}

// Round 15
// 224.161 us; speedup vs baseline: 1.1046x; 1.1046x over previous
//
#include <hip/hip_runtime.h>
#include <hip/hip_bf16.h>

#define BB 2
#define NN 8192
#define SPL 16
#define CAND (NN/SPL)
#define NPTS (BB*NN)

// ---- workspace layout (units: 4-byte words), total ~26.5 MB ----
#define POS4_OFF 0u                     /* 65,536 w float4 (x,y,z,0) */
#define PART_OFF 65536u                 /* [256][NPTS] = 4,194,304 w */
#define IDX_OFF  4259840u               /* 262,144 w */
#define WT_OFF   4521984u               /* 4 mats x 4096 bf16 = 8,192 w */
#define QB_OFF   4530176u               /* 1,048,576 w */
#define KVB_OFF  5578752u               /* 1,048,576 w packed bf16 k|v */

typedef __attribute__((ext_vector_type(8))) short bf16x8;
typedef __attribute__((ext_vector_type(4))) float f32x4;

__device__ __forceinline__ unsigned umn(unsigned a, unsigned b) {
#if __has_builtin(__builtin_elementwise_min)
  return __builtin_elementwise_min(a, b);
#else
  return a < b ? a : b;
#endif
}
__device__ __forceinline__ unsigned umx(unsigned a, unsigned b) {
#if __has_builtin(__builtin_elementwise_max)
  return __builtin_elementwise_max(a, b);
#else
  return a < b ? b : a;
#endif
}

__device__ inline unsigned short f2bf(float x) {
  __hip_bfloat16 b = __float2bfloat16(x);
  return *(unsigned short*)&b;
}

// column-block rotate swizzle for conflict-free ds_read_b128 fragments
#define HCOL(c, j) ((((((c) >> 3) + (j)) & 7) << 3) | ((c) & 7))

// ============================ MEGA1: KNN + qkv/pos4 + wt (role-split) =========
// blocks [0,1024)   : KNN batch-16 OEMS, RAW pos distance (R12-proven)
// blocks [1024,1536): pos4 staging + x=emb(feat); q,k,v via 4-pass 24KB LDS
// blocks [1536,1600): wt bf16-T staging
// 24KB static LDS keeps KNN role at 6 blocks/CU (R12 lesson: LDS is per-kernel).
__global__ __launch_bounds__(256) void mega1(
    const float* __restrict__ pos, const float* __restrict__ feat,
    const float* __restrict__ emb_w, const float* __restrict__ emb_b,
    const float* __restrict__ wq, const float* __restrict__ wk,
    const float* __restrict__ wv,
    const float* __restrict__ pe_w2, const float* __restrict__ at_w1,
    const float* __restrict__ at_w2, const float* __restrict__ out_w,
    float* __restrict__ ws)
{
  __shared__ __align__(16) float smem[6144];   // 24 KB: wl[4096] | xl[2048]
  const int tid = threadIdx.x;
  const int bx = blockIdx.x;
  float* pos4 = ws + POS4_OFF;
  unsigned* part = (unsigned*)ws + PART_OFF;
  float* qg = ws + QB_OFF;
  unsigned* kvp = (unsigned*)ws + KVB_OFF;

  if (bx < 1024) {
    // ---------------- role A: KNN (raw pos, batch-16 OEMS) ----------------
    constexpr int OE[63][2] = {
      {0,1},{2,3},{4,5},{6,7},{8,9},{10,11},{12,13},{14,15},
      {0,2},{1,3},{4,6},{5,7},{8,10},{9,11},{12,14},{13,15},
      {1,2},{5,6},{9,10},{13,14},
      {0,4},{1,5},{2,6},{3,7},{8,12},{9,13},{10,14},{11,15},
      {2,4},{3,5},{10,12},{11,13},
      {1,2},{3,4},{5,6},{9,10},{11,12},{13,14},
      {0,8},{1,9},{2,10},{3,11},{4,12},{5,13},{6,14},{7,15},
      {4,8},{5,9},{6,10},{7,11},
      {2,4},{3,5},{6,8},{7,9},{10,12},{11,13},
      {1,2},{3,4},{5,6},{7,8},{9,10},{11,12},{13,14}
    };
    const int g = (bx & 63) * 256 + tid;
    const int s = bx >> 6;
    const int bu = __builtin_amdgcn_readfirstlane(g >> 13);
    const float qx = pos[g * 3 + 0], qy = pos[g * 3 + 1], qz = pos[g * 3 + 2];
    const float* __restrict__ cp = pos + (bu * NN + s * CAND) * 3;  // uniform
    const unsigned jb = (unsigned)(s * CAND);
    unsigned m[16];
#pragma unroll
    for (int i = 0; i < 16; i++) m[i] = 0xFFFFFFFFu;
    for (int j0 = 0; j0 < CAND; j0 += 16) {
      float c[48];
#pragma unroll
      for (int i = 0; i < 48; i++) c[i] = cp[j0 * 3 + i];   // scalar loads
      unsigned b[16];
#pragma unroll
      for (int i = 0; i < 16; i++) {
        float dx = c[i * 3 + 0] - qx;
        float dy = c[i * 3 + 1] - qy;
        float dz = c[i * 3 + 2] - qz;
        float d2 = fmaf(dx, dx, fmaf(dy, dy, dz * dz));  // >=0 by construction
        b[i] = (__float_as_uint(d2) & 0xFFFFE000u) | (jb + (unsigned)(j0 + i));
      }
#pragma unroll
      for (int cc = 0; cc < 63; cc++) {        // OEMS-16 sort DESC
        const int x = OE[cc][0], y = OE[cc][1];
        unsigned lo = umn(b[x], b[y]);
        unsigned hi = umx(b[x], b[y]);
        b[x] = hi; b[y] = lo;
      }
#pragma unroll
      for (int i = 0; i < 16; i++) m[i] = umn(m[i], b[i]);
#pragma unroll
      for (int d = 8; d; d >>= 1) {            // bitonic clean -> asc
#pragma unroll
        for (int i = 0; i < 16; i++) {
          if ((i & d) == 0) {
            const int l = i | d;
            unsigned lo = umn(m[i], m[l]);
            unsigned hi = umx(m[i], m[l]);
            m[i] = lo; m[l] = hi;
          }
        }
      }
    }
#pragma unroll
    for (int i = 0; i < 16; i++)
      part[(unsigned)(s * 16 + i) * NPTS + (unsigned)g] = m[i];
  } else if (bx < 1536) {
    // ---------------- role B: pos4 + emb + qkv, 4-pass staging ----------------
    float* wl = smem;            // 4096 floats (16 KB)
    float* xl = smem + 4096;     // 2048 floats (8 KB)
    const int vb = bx - 1024;
    const int col = tid & 63;
    const int rg = tid >> 6;
    const int row0 = vb * 32 + rg * 8;
    const int rowu = __builtin_amdgcn_readfirstlane(row0);
    if (tid < 32) {              // pos4 staging: 32 points/block
      const int p = vb * 32 + tid;
      float x = pos[p * 3 + 0], y = pos[p * 3 + 1], z = pos[p * 3 + 2];
      float4 v = {x, y, z, 0.f};
      ((float4*)pos4)[p] = v;
    }
    for (int i = tid; i < 4096; i += 256) wl[i] = emb_w[i];
    __syncthreads();
    {
      float acc[8];
      float bias = emb_b[col];
#pragma unroll
      for (int r = 0; r < 8; r++) acc[r] = bias;
      for (int c = 0; c < 64; c++) {
        float w = wl[c * 64 + col];
        const float* fp = feat + rowu * 64 + c;   // uniform -> scalar loads
#pragma unroll
        for (int r = 0; r < 8; r++) acc[r] = fmaf(fp[r * 64], w, acc[r]);
      }
#pragma unroll
      for (int r = 0; r < 8; r++) xl[(rg * 8 + r) * 64 + col] = acc[r];
    }
    __syncthreads();
    for (int i = tid; i < 4096; i += 256) wl[i] = wq[i];
    __syncthreads();
    {
      float aq[8];
#pragma unroll
      for (int r = 0; r < 8; r++) aq[r] = 0.f;
      for (int c = 0; c < 64; c++) {
        float w = wl[c * 64 + col];
#pragma unroll
        for (int r = 0; r < 8; r++)
          aq[r] = fmaf(xl[(rg * 8 + r) * 64 + c], w, aq[r]);
      }
#pragma unroll
      for (int r = 0; r < 8; r++) qg[(row0 + r) * 64 + col] = aq[r];
    }
    __syncthreads();
    for (int i = tid; i < 4096; i += 256) wl[i] = wk[i];
    __syncthreads();
    float ak[8];
    {
#pragma unroll
      for (int r = 0; r < 8; r++) ak[r] = 0.f;
      for (int c = 0; c < 64; c++) {
        float w = wl[c * 64 + col];
#pragma unroll
        for (int r = 0; r < 8; r++)
          ak[r] = fmaf(xl[(rg * 8 + r) * 64 + c], w, ak[r]);
      }
    }
    __syncthreads();
    for (int i = tid; i < 4096; i += 256) wl[i] = wv[i];
    __syncthreads();
    {
      float av[8];
#pragma unroll
      for (int r = 0; r < 8; r++) av[r] = 0.f;
      for (int c = 0; c < 64; c++) {
        float w = wl[c * 64 + col];
#pragma unroll
        for (int r = 0; r < 8; r++)
          av[r] = fmaf(xl[(rg * 8 + r) * 64 + c], w, av[r]);
      }
#pragma unroll
      for (int r = 0; r < 8; r++)
        kvp[(row0 + r) * 64 + col] =
            ((unsigned)f2bf(av[r]) << 16) | (unsigned)f2bf(ak[r]);
    }
  } else {
    // ---------------- role C: wt bf16-T staging ----------------
    const int t = (bx - 1536) * 256 + tid;   // wt[m*4096+f*64+c]=W_m[c*64+f]
    const float* s;
    switch (t >> 12) {
      case 0: s = pe_w2; break;
      case 1: s = at_w1; break;
      case 2: s = at_w2; break;
      default: s = out_w; break;
    }
    const int idx = t & 4095, f = idx >> 6, c = idx & 63;
    ((unsigned short*)(ws + WT_OFF))[t] = f2bf(s[c * 64 + f]);
  }
}

// ============================ S3: merge 16 sorted 16-lists (coalesced) ========
__global__ __launch_bounds__(256) void s3_merge(const float* __restrict__ ws_ro,
                                                int* __restrict__ knn_idx)
{
  const unsigned* part = (const unsigned*)ws_ro + PART_OFF;
  const int g = blockIdx.x * 256 + threadIdx.x;
  unsigned run[16];
#pragma unroll
  for (int i = 0; i < 16; i++) run[i] = part[i * NPTS + g];
#pragma unroll
  for (int l = 1; l < SPL; l++) {
#pragma unroll
    for (int i = 0; i < 16; i++)
      run[i] = umn(run[i], part[(l * 16 + 15 - i) * NPTS + g]);
#pragma unroll
    for (int d = 8; d; d >>= 1) {
#pragma unroll
      for (int i = 0; i < 16; i++) {
        if ((i & d) == 0) {
          const int l2 = i | d;
          unsigned lo = umn(run[i], run[l2]);
          unsigned hi = umx(run[i], run[l2]);
          run[i] = lo; run[l2] = hi;
        }
      }
    }
  }
  const int base = (g >> 13) * NN;
  int outv[16];
#pragma unroll
  for (int i = 0; i < 16; i++) outv[i] = base + (int)(run[i] & 0x1FFFu);
  int4* o = (int4*)(knn_idx + g * 16);
  o[0] = make_int4(outv[0], outv[1], outv[2], outv[3]);
  o[1] = make_int4(outv[4], outv[5], outv[6], outv[7]);
  o[2] = make_int4(outv[8], outv[9], outv[10], outv[11]);
  o[3] = make_int4(outv[12], outv[13], outv[14], outv[15]);
}

// ============================ S4: MFMA fused posenc/attn/softmax/out ==========
// R13-proven exactly: Bf in regs, lb(256,2), early kv/q gathers, packed bf16
// kv, no softmax max-sub, MFMA epilogue. (R14 pairing spilled: reverted.)
__device__ inline void mv(const unsigned short* hm, const bf16x8 B[4][2],
                          const float bias[4], int ln, int s0, int s1,
                          f32x4 acc[4])
{
  bf16x8 a0 = *(const bf16x8*)(hm + ln * 64 + s0);
  bf16x8 a1 = *(const bf16x8*)(hm + ln * 64 + s1);
#pragma unroll
  for (int t = 0; t < 4; t++) {
    f32x4 a = {bias[t], bias[t], bias[t], bias[t]};
    a = __builtin_amdgcn_mfma_f32_16x16x32_bf16(a0, B[t][0], a, 0, 0, 0);
    a = __builtin_amdgcn_mfma_f32_16x16x32_bf16(a1, B[t][1], a, 0, 0, 0);
    acc[t] = a;
  }
}

__global__ __launch_bounds__(256, 2) void s4_attn(
    const float* __restrict__ ws_ro, const float* __restrict__ feat,
    const float* __restrict__ pe_w1, const float* __restrict__ pe_b1,
    const float* __restrict__ pe_b2, const float* __restrict__ at_b1,
    const float* __restrict__ at_b2, const float* __restrict__ out_b,
    const int* __restrict__ knn, float* __restrict__ out)
{
  __shared__ unsigned short hma[4][1024];   // per-wave 16x64 bf16 h (8 KB)
  __shared__ unsigned short resm[1024];     // 16 points x 64 bf16   (2 KB)
  const float* pos4 = ws_ro + POS4_OFF;
  const float* qg = ws_ro + QB_OFF;
  const unsigned* kvp = (const unsigned*)ws_ro + KVB_OFF;
  const unsigned short* wt = (const unsigned short*)(ws_ro + WT_OFF);

  const int tid = threadIdx.x;
  const int wid = tid >> 6, lane = tid & 63;
  const int ln = lane & 15, quad = lane >> 4;
  unsigned short* hm = hma[wid];
  const int s0 = ((quad + ln) & 7) << 3;
  const int s1 = ((4 + quad + ln) & 7) << 3;

  bf16x8 Bf[3][4][2];
#pragma unroll
  for (int m = 0; m < 3; m++)
#pragma unroll
    for (int t = 0; t < 4; t++)
#pragma unroll
      for (int ks = 0; ks < 2; ks++)
        Bf[m][t][ks] = *(const bf16x8*)(wt + m * 4096 + (t * 16 + ln) * 64 +
                                        ks * 32 + quad * 8);
  bf16x8 bo[2];
#pragma unroll
  for (int ks = 0; ks < 2; ks++)
    bo[ks] = *(const bf16x8*)(wt + 3 * 4096 + (wid * 16 + ln) * 64 +
                              ks * 32 + quad * 8);

  float pw10 = pe_w1[lane], pw11 = pe_w1[64 + lane], pw12 = pe_w1[128 + lane];
  float pb1 = pe_b1[lane];
  float bpe[4], ba1[4], ba2[4];
#pragma unroll
  for (int t = 0; t < 4; t++) {
    bpe[t] = pe_b2[t * 16 + ln];
    ba1[t] = at_b1[t * 16 + ln];
    ba2[t] = at_b2[t * 16 + ln];
  }
  const float4* pp4 = (const float4*)pos4;

  const int p0 = blockIdx.x * 16 + wid * 4;
  const int ps0 = __builtin_amdgcn_readfirstlane(p0);
  int4 cur[4];
  {
    const int4* ip4 = (const int4*)(knn + ps0 * 16);
#pragma unroll
    for (int u = 0; u < 4; u++) cur[u] = ip4[u];
  }

  for (int pp = 0; pp < 4; pp++) {
    const int p = p0 + pp;
    const int ps = __builtin_amdgcn_readfirstlane(p);
    int jj[16];
#pragma unroll
    for (int u = 0; u < 4; u++) {
      jj[u*4+0] = cur[u].x; jj[u*4+1] = cur[u].y;
      jj[u*4+2] = cur[u].z; jj[u*4+3] = cur[u].w;
    }
    int4 nxt[4];
    {
      const int pn = (pp < 3) ? (ps + 1) : ps;
      const int4* np4 = (const int4*)(knn + pn * 16);
#pragma unroll
      for (int u = 0; u < 4; u++) nxt[u] = np4[u];
    }
    unsigned kvw[4][4];                    // early gathers (hide under mv1)
#pragma unroll
    for (int r = 0; r < 4; r++) {
      const unsigned* kp = kvp + jj[quad * 4 + r] * 64 + ln;
#pragma unroll
      for (int t = 0; t < 4; t++) kvw[r][t] = kp[t * 16];
    }
    float qv[4];
#pragma unroll
    for (int t = 0; t < 4; t++) qv[t] = qg[p * 64 + t * 16 + ln];

    const float4 mp = pp4[ps];
#pragma unroll
    for (int j = 0; j < 16; j++) {
      const float4 np = pp4[jj[j]];
      float h1 = fmaf(np.z - mp.z, pw12,
                 fmaf(np.y - mp.y, pw11,
                 fmaf(np.x - mp.x, pw10, pb1)));
      hm[j * 64 + HCOL(lane, j)] = f2bf(fmaxf(h1, 0.f));
    }
    f32x4 accp[4];
    mv(hm, Bf[0], bpe, ln, s0, s1, accp);          // posenc
    float vpe[4][4];
#pragma unroll
    for (int r = 0; r < 4; r++) {
      const int j = quad * 4 + r;
#pragma unroll
      for (int t = 0; t < 4; t++) {
        const unsigned w = kvw[r][t];
        float kf = __uint_as_float(w << 16);
        float vf = __uint_as_float(w & 0xFFFF0000u);
        float pe = accp[t][r];
        vpe[t][r] = vf + pe;
        hm[j * 64 + HCOL(t * 16 + ln, j)] = f2bf(qv[t] - kf + pe);
      }
    }
    f32x4 acch[4];
    mv(hm, Bf[1], ba1, ln, s0, s1, acch);          // hh @ at_w1 + b
#pragma unroll
    for (int t = 0; t < 4; t++)
#pragma unroll
      for (int r = 0; r < 4; r++) {
        const int j = quad * 4 + r;
        hm[j * 64 + HCOL(t * 16 + ln, j)] = f2bf(fmaxf(acch[t][r], 0.f));
      }
    f32x4 lg[4];
    mv(hm, Bf[2], ba2, ln, s0, s1, lg);            // logits
    const int pb = wid * 4 + pp;
#pragma unroll
    for (int t = 0; t < 4; t++) {                  // softmax (tiny logits)
      float e0 = __expf(lg[t][0] * 0.125f);
      float e1 = __expf(lg[t][1] * 0.125f);
      float e2 = __expf(lg[t][2] * 0.125f);
      float e3 = __expf(lg[t][3] * 0.125f);
      float ss = (e0 + e1) + (e2 + e3);
      float dt = fmaf(e3, vpe[t][3], fmaf(e2, vpe[t][2],
                 fmaf(e1, vpe[t][1], e0 * vpe[t][0])));
      ss += __shfl_xor(ss, 16); ss += __shfl_xor(ss, 32);
      dt += __shfl_xor(dt, 16); dt += __shfl_xor(dt, 32);
      float res = dt / ss;
      if (quad == 0) resm[pb * 64 + HCOL(t * 16 + ln, pb)] = f2bf(res);
    }
#pragma unroll
    for (int u = 0; u < 4; u++) cur[u] = nxt[u];
  }
  __syncthreads();
  {
    const int nt = wid;
    float ob = out_b[nt * 16 + ln];
    f32x4 acc = {ob, ob, ob, ob};
#pragma unroll
    for (int ks = 0; ks < 2; ks++) {
      bf16x8 a = *(const bf16x8*)(resm + ln * 64 +
                                  (((ks * 4 + quad + ln) & 7) << 3));
      acc = __builtin_amdgcn_mfma_f32_16x16x32_bf16(a, bo[ks], acc, 0, 0, 0);
    }
#pragma unroll
    for (int r = 0; r < 4; r++) {
      const int pt = blockIdx.x * 16 + quad * 4 + r;
      const int f = nt * 16 + ln;
      out[pt * 64 + f] = acc[r] + feat[pt * 64 + f];
    }
  }
}

// ============================ launcher ========================================
extern "C" void kernel_launch(void* const* d_in, const int* in_sizes, int n_in,
                              void* d_out, int out_size, void* d_ws, size_t ws_size,
                              hipStream_t stream)
{
  (void)in_sizes; (void)n_in; (void)out_size; (void)ws_size;
  const float* pos   = (const float*)d_in[0];
  const float* feat  = (const float*)d_in[1];
  const float* emb_w = (const float*)d_in[2];
  const float* emb_b = (const float*)d_in[3];
  const float* wq    = (const float*)d_in[4];
  const float* wk    = (const float*)d_in[5];
  const float* wv    = (const float*)d_in[6];
  const float* pe_w1 = (const float*)d_in[7];
  const float* pe_b1 = (const float*)d_in[8];
  const float* pe_w2 = (const float*)d_in[9];
  const float* pe_b2 = (const float*)d_in[10];
  const float* at_w1 = (const float*)d_in[11];
  const float* at_b1 = (const float*)d_in[12];
  const float* at_w2 = (const float*)d_in[13];
  const float* at_b2 = (const float*)d_in[14];
  const float* out_w = (const float*)d_in[15];
  const float* out_b = (const float*)d_in[16];
  float* ws = (float*)d_ws;

  mega1<<<1600, 256, 0, stream>>>(pos, feat, emb_w, emb_b, wq, wk, wv,
                                  pe_w2, at_w1, at_w2, out_w, ws);
  s3_merge<<<64, 256, 0, stream>>>(ws, (int*)ws + IDX_OFF);
  s4_attn<<<NPTS / 16, 256, 0, stream>>>(ws, feat, pe_w1, pe_b1, pe_b2,
      at_b1, at_b2, out_b, (int*)ws + IDX_OFF, (float*)d_out);
}